// Round 8
// baseline (396.165 us; speedup 1.0000x reference)
//
#include <hip/hip_runtime.h>

// Dims
#define NB 8
#define NC 32
#define NCP 33
#define NW 256
#define NH 128
#define NX 720
#define NY 361

typedef __attribute__((ext_vector_type(8)))  short short8;
typedef __attribute__((ext_vector_type(4)))  float f32x4;
typedef __attribute__((ext_vector_type(16))) float f32x16;

// fp32 -> bf16 round-to-nearest-even
static __device__ __forceinline__ unsigned short f2bf(float f) {
    union { float f; unsigned int u; } v; v.f = f;
    unsigned int r = (v.u + 0x7FFFu + ((v.u >> 16) & 1u)) >> 16;
    return (unsigned short)r;
}

// Async global->LDS, 16B per lane. LDS dest is wave-uniform base + lane*16
// (linear, unpadded); global src is per-lane.
#define GLD16(gp, lp)                                                    \
    __builtin_amdgcn_global_load_lds(                                    \
        (const __attribute__((address_space(1))) unsigned int*)(gp),     \
        (__attribute__((address_space(3))) unsigned int*)(lp), 16, 0, 0)

// K1: w0t[b][x][w] bf16
__global__ __launch_bounds__(256) void rbf_w0_kernel(
    const float* __restrict__ lon_in, const float* __restrict__ lon_out,
    const float* __restrict__ ls, unsigned short* __restrict__ w0t)
{
    int idx = blockIdx.x * 256 + threadIdx.x;   // exact grid: 8*720*256
    int w = idx & (NW - 1);
    int r = idx >> 8;
    int x = r % NX;
    int b = r / NX;
    float l = ls[0];
    float inv = -0.5f / (l * l);
    float d = lon_in[b * NW + w] - lon_out[b * NX + x];
    w0t[idx] = f2bf(__expf(inv * d * d));
}

// K2: w1t[b][y][h] bf16
__global__ __launch_bounds__(256) void rbf_w1_kernel(
    const float* __restrict__ lat_in, const float* __restrict__ lat_out,
    const float* __restrict__ ls, unsigned short* __restrict__ w1t)
{
    int idx = blockIdx.x * 256 + threadIdx.x;   // exact grid: 8*361*128
    int h = idx & (NH - 1);
    int r = idx >> 7;
    int y = r % NY;
    int b = r / NY;
    float l = ls[0];
    float inv = -0.5f / (l * l);
    float d = lat_in[b * NH + h] - lat_out[b * NY + y];
    w1t[idx] = f2bf(__expf(inv * d * d));
}

// K3: wtT[b][c(33)][h(128)][w(256)] bf16 — transposed, NaN-fixed, c=0 = density mask.
__global__ __launch_bounds__(256) void prep_wtT_kernel(
    const float* __restrict__ wt, unsigned short* __restrict__ wtT)
{
    __shared__ float tile[64 * 129];
    const int bc = blockIdx.z;
    const int b = bc / NCP;
    const int c = bc - b * NCP;
    const int w0 = blockIdx.x * 64;
    const bool dens = (c == 0);
    const float* src = wt + ((size_t)b * NC + (dens ? 0 : (c - 1))) * (NW * NH);

    const int r4 = threadIdx.x >> 5;   // 0..7
    const int c4 = threadIdx.x & 31;   // float4 col
    #pragma unroll
    for (int p = 0; p < 8; ++p) {
        int r = r4 + p * 8;
        float4 v = *(const float4*)&src[(size_t)(w0 + r) * NH + c4 * 4];
        float o0 = (v.x != v.x) ? 0.f : (dens ? 1.f : v.x);
        float o1 = (v.y != v.y) ? 0.f : (dens ? 1.f : v.y);
        float o2 = (v.z != v.z) ? 0.f : (dens ? 1.f : v.z);
        float o3 = (v.w != v.w) ? 0.f : (dens ? 1.f : v.w);
        float* tp = &tile[r * 129 + c4 * 4];
        tp[0] = o0; tp[1] = o1; tp[2] = o2; tp[3] = o3;
    }
    __syncthreads();

    unsigned short* dst = wtT + (size_t)bc * (NH * NW);
    #pragma unroll
    for (int p = 0; p < 4; ++p) {
        int ch = threadIdx.x + p * 256;
        int wc = ch & 7;          // which 8-w chunk in this 64-w tile
        int h  = ch >> 3;         // 0..127
        unsigned int u[4];
        #pragma unroll
        for (int j = 0; j < 4; ++j) {
            unsigned int lo = f2bf(tile[(wc * 8 + 2 * j    ) * 129 + h]);
            unsigned int hi = f2bf(tile[(wc * 8 + 2 * j + 1) * 129 + h]);
            u[j] = lo | (hi << 16);
        }
        uint4 q = make_uint4(u[0], u[1], u[2], u[3]);
        *(uint4*)&dst[(size_t)h * NW + w0 + wc * 8] = q;
    }
}

// Stage 1: T[bc][x][h] = sum_w w0t[b][x][w] * wtT[bc][h][w]
// 128x128 tile, BK=64, 4 waves of 2x2 32x32x16 fragments.
// R8: staging via global_load_lds width=16 (m97/m193 recipe: +67% isolated).
// LDS tiles are LINEAR [128][64] (gload_lds requires contiguous dest);
// fragment-read bank conflicts are timing-invisible at 2-phase (m252/m97).
// MFMA order identical to R7 -> bit-identical T.
__global__ __launch_bounds__(256, 4) void stage1_gemm(
    const unsigned short* __restrict__ w0t,
    const unsigned short* __restrict__ wtT,
    unsigned short* __restrict__ tbuf)
{
    __shared__ __align__(16) unsigned short As[128 * 64];
    __shared__ __align__(16) unsigned short Bs[128 * 64];

    const int x0 = blockIdx.x * 128;
    const int bc = blockIdx.y;
    const int b  = bc / NCP;

    const int tid  = threadIdx.x;
    const int lane = tid & 63;
    const int wv   = tid >> 6;
    const int l31  = lane & 31;
    const int lk   = lane >> 5;
    const int mw   = (wv & 1) * 64;
    const int nw   = (wv >> 1) * 64;

    const unsigned short* Ap = w0t + (size_t)b * NX * NW;
    const unsigned short* Bp = wtT + (size_t)bc * NH * NW;

    f32x16 acc[2][2];
    #pragma unroll
    for (int i = 0; i < 2; ++i)
        #pragma unroll
        for (int j = 0; j < 2; ++j)
            #pragma unroll
            for (int e = 0; e < 16; ++e) acc[i][j][e] = 0.f;

    for (int k0 = 0; k0 < NW; k0 += 64) {
        // Stage A (128x64) + B (128x64) via async global->LDS.
        // Per call p: this thread handles 16B chunk (p*256 + tid);
        // a wave's 64 chunks are LDS-contiguous (1 KB span) -> linear dest.
        #pragma unroll
        for (int p = 0; p < 4; ++p) {
            int off16 = p * 256 + tid;        // 0..1023
            int r  = off16 >> 3;              // row 0..127 (8 chunks/row)
            int cc = (off16 & 7) * 8;         // short col
            int xr = x0 + r; if (xr > NX - 1) xr = NX - 1;
            const unsigned short* ga = &Ap[(size_t)xr * NW + k0 + cc];
            const unsigned short* gb = &Bp[(size_t)r  * NW + k0 + cc];
            unsigned short* la = &As[(p * 256 + wv * 64) * 8];   // wave-uniform
            unsigned short* lb = &Bs[(p * 256 + wv * 64) * 8];
            GLD16(ga, la);
            GLD16(gb, lb);
        }
        __syncthreads();
        #pragma unroll
        for (int ks = 0; ks < 4; ++ks) {
            const int ko = ks * 16 + lk * 8;
            short8 a0 = *(const short8*)&As[(mw      + l31) * 64 + ko];
            short8 a1 = *(const short8*)&As[(mw + 32 + l31) * 64 + ko];
            short8 b0 = *(const short8*)&Bs[(nw      + l31) * 64 + ko];
            short8 b1 = *(const short8*)&Bs[(nw + 32 + l31) * 64 + ko];
            acc[0][0] = __builtin_amdgcn_mfma_f32_32x32x16_bf16(a0, b0, acc[0][0], 0, 0, 0);
            acc[0][1] = __builtin_amdgcn_mfma_f32_32x32x16_bf16(a0, b1, acc[0][1], 0, 0, 0);
            acc[1][0] = __builtin_amdgcn_mfma_f32_32x32x16_bf16(a1, b0, acc[1][0], 0, 0, 0);
            acc[1][1] = __builtin_amdgcn_mfma_f32_32x32x16_bf16(a1, b1, acc[1][1], 0, 0, 0);
        }
        __syncthreads();
    }

    unsigned short* Tp = tbuf + (size_t)bc * NX * NH;
    #pragma unroll
    for (int mi = 0; mi < 2; ++mi)
        #pragma unroll
        for (int ni = 0; ni < 2; ++ni)
            #pragma unroll
            for (int r = 0; r < 16; ++r) {
                int rowf = (r & 3) + 8 * (r >> 2) + 4 * lk;
                int x = x0 + mw + mi * 32 + rowf;
                if (x < NX)
                    Tp[(size_t)x * NH + nw + ni * 32 + l31] = f2bf(acc[mi][ni][r]);
            }
}

// Density kernel: plane c=0 of one b, 32 x-rows x full y.
// Writes BOTH out[b*NCP+0] (final output, nt-store) and densbuf[b][x][y].
// Unchanged (passing, bit-identical density values).
__global__ __launch_bounds__(256, 3) void dens_kernel(
    const unsigned short* __restrict__ tbuf,
    const unsigned short* __restrict__ w1t,
    float* __restrict__ out,
    float* __restrict__ densbuf)
{
    __shared__ __align__(16) float Os[32 * NY];

    const int x0 = blockIdx.x * 32;
    const int b  = blockIdx.y;

    const int tid  = threadIdx.x;
    const int lane = tid & 63;
    const int wv   = tid >> 6;
    const int l31  = lane & 31;
    const int lk   = lane >> 5;

    const unsigned short* __restrict__ Tp = tbuf + (size_t)(b * NCP) * NX * NH;
    const unsigned short* __restrict__ Vp = w1t + (size_t)b * NY * NH;

    int xA = x0 + l31; if (xA > NX - 1) xA = NX - 1;
    const size_t arow = (size_t)xA * NH;

    int yc[3];
    #pragma unroll
    for (int ni = 0; ni < 3; ++ni) {
        int y = wv * 96 + ni * 32 + l31;
        yc[ni] = (y > NY - 1) ? (NY - 1) : y;
    }

    f32x16 aee[3];
    #pragma unroll
    for (int ni = 0; ni < 3; ++ni)
        #pragma unroll
        for (int e = 0; e < 16; ++e) aee[ni][e] = 0.f;

    #pragma unroll
    for (int ks = 0; ks < 8; ++ks) {
        const int ko = ks * 16 + lk * 8;
        short8 a = *(const short8*)&Tp[arow + ko];
        #pragma unroll
        for (int ni = 0; ni < 3; ++ni) {
            short8 bb = *(const short8*)&Vp[(size_t)yc[ni] * NH + ko];
            aee[ni] = __builtin_amdgcn_mfma_f32_32x32x16_bf16(a, bb, aee[ni], 0, 0, 0);
        }
    }

    #pragma unroll
    for (int ni = 0; ni < 3; ++ni) {
        const int y = wv * 96 + ni * 32 + l31;
        if (y < NY) {
            #pragma unroll
            for (int r = 0; r < 16; ++r) {
                int xl = (r & 3) + 8 * (r >> 2) + 4 * lk;
                Os[xl * NY + y] = aee[ni][r];
            }
        }
    }
    __syncthreads();

    const int rows_eff = (NX - x0 < 32) ? (NX - x0) : 32;
    const int n4 = rows_eff * NY / 4;
    f32x4* __restrict__ Cb =
        (f32x4*)(out + (size_t)(b * NCP) * NX * NY + (size_t)x0 * NY);
    f32x4* __restrict__ Db =
        (f32x4*)(densbuf + (size_t)b * NX * NY + (size_t)x0 * NY);
    const f32x4* Os4 = (const f32x4*)Os;
    for (int g = tid; g < n4; g += 256) {
        f32x4 o = Os4[g];
        __builtin_nontemporal_store(o, &Cb[g]);   // final output: stream, no reuse
        Db[g] = o;                                 // densbuf: cached, re-read soon
    }
}

// Stage 2 main, CPB=4 channels per block. Unchanged from R7 (passing).
__global__ __launch_bounds__(256, 2) void stage2_main(
    const unsigned short* __restrict__ tbuf,
    const unsigned short* __restrict__ w1t,
    const float* __restrict__ densbuf,
    float* __restrict__ out)
{
    __shared__ __align__(16) float Os[32 * NY];

    const int x0 = blockIdx.x * 32;
    const int bg = blockIdx.y;           // 0..63
    const int b  = bg >> 3;
    const int cg = bg & 7;               // channels 1+cg*4 .. 1+cg*4+3

    const int tid  = threadIdx.x;
    const int lane = tid & 63;
    const int wv   = tid >> 6;
    const int l31  = lane & 31;
    const int lk   = lane >> 5;

    const unsigned short* __restrict__ Vp = w1t + (size_t)b * NY * NH;

    int xA = x0 + l31; if (xA > NX - 1) xA = NX - 1;
    const size_t arow = (size_t)xA * NH;

    int yc[3];
    #pragma unroll
    for (int ni = 0; ni < 3; ++ni) {
        int y = wv * 96 + ni * 32 + l31;
        yc[ni] = (y > NY - 1) ? (NY - 1) : y;
    }

    // Load all 24 B fragments once; held in registers for the channel loop.
    short8 bfr[8][3];
    #pragma unroll
    for (int ks = 0; ks < 8; ++ks)
        #pragma unroll
        for (int ni = 0; ni < 3; ++ni)
            bfr[ks][ni] = *(const short8*)&Vp[(size_t)yc[ni] * NH + ks * 16 + lk * 8];

    const int rows_eff = (NX - x0 < 32) ? (NX - x0) : 32;
    const int n4 = rows_eff * NY / 4;
    const f32x4* __restrict__ Db =
        (const f32x4*)(densbuf + (size_t)b * NX * NY + (size_t)x0 * NY);
    const f32x4* Os4 = (const f32x4*)Os;

    #pragma unroll
    for (int ci = 0; ci < 4; ++ci) {
        const int bcy = b * NCP + 1 + cg * 4 + ci;
        const unsigned short* __restrict__ Tp = tbuf + (size_t)bcy * NX * NH;

        f32x16 aee[3];
        #pragma unroll
        for (int ni = 0; ni < 3; ++ni)
            #pragma unroll
            for (int e = 0; e < 16; ++e) aee[ni][e] = 0.f;

        #pragma unroll
        for (int ks = 0; ks < 8; ++ks) {
            short8 a = *(const short8*)&Tp[arow + ks * 16 + lk * 8];
            aee[0] = __builtin_amdgcn_mfma_f32_32x32x16_bf16(a, bfr[ks][0], aee[0], 0, 0, 0);
            aee[1] = __builtin_amdgcn_mfma_f32_32x32x16_bf16(a, bfr[ks][1], aee[1], 0, 0, 0);
            aee[2] = __builtin_amdgcn_mfma_f32_32x32x16_bf16(a, bfr[ks][2], aee[2], 0, 0, 0);
        }

        #pragma unroll
        for (int ni = 0; ni < 3; ++ni) {
            const int y = wv * 96 + ni * 32 + l31;
            if (y < NY) {
                #pragma unroll
                for (int r = 0; r < 16; ++r) {
                    int xl = (r & 3) + 8 * (r >> 2) + 4 * lk;
                    Os[xl * NY + y] = aee[ni][r];
                }
            }
        }
        __syncthreads();

        f32x4* __restrict__ Cb =
            (f32x4*)(out + (size_t)bcy * NX * NY + (size_t)x0 * NY);
        for (int g = tid; g < n4; g += 256) {
            f32x4 o = Os4[g];
            f32x4 d = Db[g];
            o.x /= fminf(fmaxf(d.x, 1e-6f), 1e5f);
            o.y /= fminf(fmaxf(d.y, 1e-6f), 1e5f);
            o.z /= fminf(fmaxf(d.z, 1e-6f), 1e5f);
            o.w /= fminf(fmaxf(d.w, 1e-6f), 1e5f);
            __builtin_nontemporal_store(o, &Cb[g]);
        }
        __syncthreads();   // Os free before next channel overwrites it
    }
}

extern "C" void kernel_launch(void* const* d_in, const int* in_sizes, int n_in,
                              void* d_out, int out_size, void* d_ws, size_t ws_size,
                              hipStream_t stream)
{
    const float* wt      = (const float*)d_in[0];
    const float* lon_in  = (const float*)d_in[1];
    const float* lat_in  = (const float*)d_in[2];
    const float* lon_out = (const float*)d_in[3];
    const float* lat_out = (const float*)d_in[4];
    const float* ls      = (const float*)d_in[5];
    float* out = (float*)d_out;

    // Workspace (ushort): w0t | w1t | wtT | T  — ~69.7 MB.
    // densbuf (8.3 MB fp32) OVERLAYS wtT (dead after stage1, stream-ordered).
    unsigned short* w0t  = (unsigned short*)d_ws;
    unsigned short* w1t  = w0t + (size_t)NB * NX * NW;            // 1,474,560
    unsigned short* wtT  = w1t + (size_t)NB * NY * NH;            // +369,664
    unsigned short* tbuf = wtT + (size_t)NB * NCP * NH * NW;      // +8,650,752
    float* densbuf = (float*)wtT;   // 16B-aligned (offset 3,688,448 B)

    rbf_w0_kernel<<<(NB * NX * NW) / 256, 256, 0, stream>>>(lon_in, lon_out, ls, w0t);
    rbf_w1_kernel<<<(NB * NY * NH) / 256, 256, 0, stream>>>(lat_in, lat_out, ls, w1t);

    dim3 g3(4, 1, NB * NCP);
    prep_wtT_kernel<<<g3, 256, 0, stream>>>(wt, wtT);

    dim3 g1(6, NB * NCP);                    // 6 x-tiles x 264 (b,c)
    stage1_gemm<<<g1, 256, 0, stream>>>(w0t, wtT, tbuf);

    dim3 gd(23, NB);                         // density: 23 x-tiles x 8 b
    dens_kernel<<<gd, 256, 0, stream>>>(tbuf, w1t, out, densbuf);

    dim3 g2(23, NB * 8);                     // 23 x-tiles x (8 b x 8 c-groups)
    stage2_main<<<g2, 256, 0, stream>>>(tbuf, w1t, densbuf, out);
}